// Round 8
// baseline (112.858 us; speedup 1.0000x reference)
//
#include <hip/hip_runtime.h>
#include <hip/hip_bf16.h>

#define IN_DIM 128
#define HEADS 4
#define ODIM 32
#define HD (HEADS * ODIM) // 128
#define NEG_SLOPE 0.2f

#define GM 64             // nodes per block in MFMA GEMM
#define LDK 136           // padded k-stride (bf16 elems)

#define BIN_SHIFT 5
#define BIN_NODES 32      // dst nodes per bin
#define BINCAP 1024       // max edges per bin (mean 512)
#define MAXBINS 2048      // LDS sizing in k_bin (nbins = 1563 for N=50000)
#define KE 16             // edges per thread in k_bin

typedef unsigned short ushortT;
typedef __attribute__((ext_vector_type(8))) short bf16x8;
typedef __attribute__((ext_vector_type(4))) float f32x4;

static __device__ __forceinline__ ushortT f2bf(float f) {
    __hip_bfloat16 b = __float2bfloat16(f); // RNE
    return *reinterpret_cast<ushortT*>(&b);
}
static __device__ __forceinline__ float bf2f(ushortT u) {
    unsigned int x = ((unsigned int)u) << 16;
    return __uint_as_float(x);
}

// ---------------------------------------------------------------------------
// One-time W convert+transpose: Wt_g[c][k] = bf16(W[k][c]). 16384 elems.
// ---------------------------------------------------------------------------
__global__ void __launch_bounds__(256) k_wconv(
    const float* __restrict__ W, ushortT* __restrict__ Wt_g)
{
    const int idx = blockIdx.x * 256 + threadIdx.x;  // 0..16383
    const int c = idx >> 7, k = idx & 127;
    Wt_g[c * 128 + k] = f2bf(W[k * HD + c]);         // write coalesced in k
}

// ---------------------------------------------------------------------------
// Kernel 1: h = x @ W via bf16 MFMA (16x16x32), fp32 accumulate.
// Output: 4 head-planes h_pl[h][N][32] bf16 (each 3.2MB -> per-XCD L2 fits).
// ---------------------------------------------------------------------------
__global__ void __launch_bounds__(256) k_gemm_mfma(
    const float* __restrict__ x, const ushortT* __restrict__ Wt_g,
    ushortT* __restrict__ h_pl, int N)
{
    __shared__ ushortT Xs[GM * LDK];
    __shared__ ushortT Wt[128 * LDK];

    const int t  = threadIdx.x;
    const int n0 = blockIdx.x * GM;

    {   // stage Wt: pure vector copy (pre-transposed bf16 global)
#pragma unroll
        for (int it = 0; it < 8; ++it) {
            const int o = it * 2048 + t * 8;      // linear ushort offset
            *reinterpret_cast<uint4*>(&Wt[(o >> 7) * LDK + (o & 127)]) =
                *reinterpret_cast<const uint4*>(&Wt_g[o]);
        }
    }
    {   // stage x as bf16: Xs[r][k]
        const int r  = t >> 2;          // 0..63
        const int k0 = (t & 3) * 32;
        const int ng = n0 + r;
        if (ng < N) {
#pragma unroll
            for (int kk = 0; kk < 32; kk += 4) {
                float4 v = *reinterpret_cast<const float4*>(
                    &x[(size_t)ng * IN_DIM + k0 + kk]);
                ushort4 u;
                u.x = f2bf(v.x); u.y = f2bf(v.y); u.z = f2bf(v.z); u.w = f2bf(v.w);
                *reinterpret_cast<ushort4*>(&Xs[r * LDK + k0 + kk]) = u;
            }
        } else {
#pragma unroll
            for (int kk = 0; kk < 32; kk += 4)
                *reinterpret_cast<ushort4*>(&Xs[r * LDK + k0 + kk]) =
                    make_ushort4(0, 0, 0, 0);
        }
    }
    __syncthreads();

    const int w  = t >> 6;          // wave 0..3 -> rows w*16
    const int l  = t & 63;
    const int lr = l & 15;
    const int lk = (l >> 4) * 8;

    f32x4 acc[8];
#pragma unroll
    for (int i = 0; i < 8; ++i) acc[i] = (f32x4)(0.f);

#pragma unroll
    for (int kt = 0; kt < 4; ++kt) {
        const bf16x8 af = *reinterpret_cast<const bf16x8*>(
            &Xs[(w * 16 + lr) * LDK + kt * 32 + lk]);
#pragma unroll
        for (int ct = 0; ct < 8; ++ct) {
            const bf16x8 bfr = *reinterpret_cast<const bf16x8*>(
                &Wt[(ct * 16 + lr) * LDK + kt * 32 + lk]);
            acc[ct] = __builtin_amdgcn_mfma_f32_16x16x32_bf16(af, bfr, acc[ct],
                                                              0, 0, 0);
        }
    }

    // C layout: col = l&15 (=lr), row = (l>>4)*4 + j.
    // col c = ct*16+lr -> head = ct>>1, dim = (ct&1)*16 + lr.
    const int rbase = w * 16 + (l >> 4) * 4;
#pragma unroll
    for (int ct = 0; ct < 8; ++ct) {
        const size_t pb = (size_t)(ct >> 1) * N * 32 + (ct & 1) * 16 + lr;
#pragma unroll
        for (int j = 0; j < 4; ++j) {
            const int ng = n0 + rbase + j;
            if (ng < N)
                h_pl[pb + (size_t)ng * 32] = f2bf(acc[ct][j]);
        }
    }
}

// ---------------------------------------------------------------------------
// Kernel 1b: per-node attention scalars (head planes).
// One wave per node: group head=l>>4, lane q=l&15 holds dims 2q,2q+1.
// ---------------------------------------------------------------------------
__global__ void __launch_bounds__(256) k_s(
    const ushortT* __restrict__ h_pl,
    const float* __restrict__ a_src, const float* __restrict__ a_dst,
    float* __restrict__ s_srcH, float* __restrict__ s_dstH, int N)
{
    const int wid = (blockIdx.x * blockDim.x + threadIdx.x) >> 6;
    if (wid >= N) return;
    const int l = threadIdx.x & 63;
    const int head = l >> 4, q = l & 15;

    const float as0 = a_src[head * 32 + 2 * q], as1 = a_src[head * 32 + 2 * q + 1];
    const float ad0 = a_dst[head * 32 + 2 * q], ad1 = a_dst[head * 32 + 2 * q + 1];

    const unsigned int pk = *reinterpret_cast<const unsigned int*>(
        &h_pl[(size_t)head * N * 32 + (size_t)wid * 32 + 2 * q]);
    const float f0 = bf2f((ushortT)(pk & 0xFFFF));
    const float f1 = bf2f((ushortT)(pk >> 16));

    float ps = f0 * as0 + f1 * as1;
    float pd = f0 * ad0 + f1 * ad1;
#pragma unroll
    for (int o = 1; o <= 8; o <<= 1) {
        ps += __shfl_xor(ps, o, 64);
        pd += __shfl_xor(pd, o, 64);
    }
    if (q == 0) {
        s_srcH[(size_t)head * N + wid] = ps;
        s_dstH[(size_t)head * N + wid] = pd;
    }
}

// ---------------------------------------------------------------------------
// Pass A: LDS-staged binning (proven, unchanged).
// ---------------------------------------------------------------------------
__global__ void __launch_bounds__(256) k_bin(
    const int* __restrict__ src, const int* __restrict__ dst,
    int* __restrict__ bin_cursor, int* __restrict__ bin_buf,
    int E, int nbins)
{
    __shared__ int lcnt[MAXBINS];
    __shared__ int lcur[MAXBINS];
    const int t = threadIdx.x;
    for (int i = t; i < nbins; i += 256) lcnt[i] = 0;
    __syncthreads();

    const int base_e = blockIdx.x * (256 * KE);
    int b_[KE]; int p_[KE];
#pragma unroll
    for (int k = 0; k < KE; ++k) {
        const int e = base_e + k * 256 + t;
        if (e < E) {
            const int d = dst[e];
            const int s = src[e];
            b_[k] = d >> BIN_SHIFT;
            p_[k] = ((d & (BIN_NODES - 1)) << 16) | s;
            atomicAdd(&lcnt[b_[k]], 1);
        } else {
            b_[k] = -1;
        }
    }
    __syncthreads();
    for (int i = t; i < nbins; i += 256) {
        const int c = lcnt[i];
        lcur[i] = (c > 0) ? atomicAdd(&bin_cursor[i], c) : 0;
    }
    __syncthreads();
#pragma unroll
    for (int k = 0; k < KE; ++k) {
        if (b_[k] >= 0) {
            const int pos = atomicAdd(&lcur[b_[k]], 1);
            if (pos < BINCAP) bin_buf[b_[k] * BINCAP + pos] = p_[k];
        }
    }
}

// ---------------------------------------------------------------------------
// Head-split pull: grid (nbins, HEADS), head = slow dispatch dim so one
// 3.2MB head plane is L2-resident per XCD at a time. 16 lanes per edge,
// 16 edges in flight per wave. Writes bf16 tmp plane (alpha-normalized,
// 1/4 folded). No atomics.
// ---------------------------------------------------------------------------
__global__ void __launch_bounds__(256) k_pull_h(
    const int* __restrict__ bin_buf, const int* __restrict__ bin_cursor,
    const ushortT* __restrict__ h_pl,
    const float* __restrict__ s_srcH, const float* __restrict__ s_dstH,
    ushortT* __restrict__ tmp, int N)
{
    __shared__ ushortT csr[BINCAP];
    __shared__ int cnt_s[BIN_NODES], start_s[BIN_NODES], cur_s[BIN_NODES];

    const int b  = blockIdx.x;
    const int hh = blockIdx.y;
    const int t  = threadIdx.x;
    const int node0 = b << BIN_SHIFT;

    int nedge = bin_cursor[b];
    nedge = (nedge < BINCAP) ? nedge : BINCAP;

    if (t < BIN_NODES) cnt_s[t] = 0;
    __syncthreads();

    for (int i = t; i < nedge; i += 256)
        atomicAdd(&cnt_s[bin_buf[b * BINCAP + i] >> 16], 1);
    __syncthreads();

    if (t < 32) {
        const int v = cnt_s[t];
        int inc = v;
#pragma unroll
        for (int o = 1; o < 32; o <<= 1) {
            const int x = __shfl_up(inc, o, 32);
            if (t >= o) inc += x;
        }
        start_s[t] = inc - v;
        cur_s[t]   = inc - v;
    }
    __syncthreads();

    for (int i = t; i < nedge; i += 256) {
        const int p = bin_buf[b * BINCAP + i];
        const int pos = atomicAdd(&cur_s[p >> 16], 1);
        csr[pos] = (ushortT)(p & 0xFFFF);
    }
    __syncthreads();

    const int wv = t >> 6;
    const int l  = t & 63;
    const int g  = l >> 4;       // edge group 0..3
    const int q  = l & 15;       // dim-pair within head

    const float* ss = s_srcH + (size_t)hh * N;
    const unsigned int* hpu = reinterpret_cast<const unsigned int*>(
        h_pl + (size_t)hh * N * 32);   // 16 uints per node (32 bf16 dims)

    for (int k = 0; k < 8; ++k) {
        const int nloc = wv * 8 + k;
        const int n = node0 + nloc;
        if (n >= N) break;

        const int st  = start_s[nloc];
        const int deg = cnt_s[nloc];
        ushortT* tp = &tmp[((size_t)hh * N + n) * 32];

        if (deg == 0) {
            if (l < 16) *reinterpret_cast<unsigned int*>(&tp[2 * q]) = 0u;
            continue;
        }

        const float vd = s_dstH[(size_t)hh * N + n];   // wave-uniform

        float den = 0.f, a0 = 0.f, a1 = 0.f;

        for (int j = 0; j < deg; j += 16) {
            const int e0 = j + g, e1 = e0 + 4, e2 = e0 + 8, e3 = e0 + 12;
            const bool v0 = e0 < deg, v1 = e1 < deg, v2 = e2 < deg, v3 = e3 < deg;
            const int s0 = csr[st + (v0 ? e0 : 0)];
            const int s1 = csr[st + (v1 ? e1 : 0)];
            const int s2 = csr[st + (v2 ? e2 : 0)];
            const int s3 = csr[st + (v3 ? e3 : 0)];

            // 8 independent loads in flight (4 broadcast + 4 line-gathers)
            const float z0 = ss[s0];
            const float z1 = ss[s1];
            const float z2 = ss[s2];
            const float z3 = ss[s3];
            const unsigned int p0 = hpu[s0 * 16 + q];
            const unsigned int p1 = hpu[s1 * 16 + q];
            const unsigned int p2 = hpu[s2 * 16 + q];
            const unsigned int p3 = hpu[s3 * 16 + q];

            float y0 = z0 + vd, y1 = z1 + vd, y2 = z2 + vd, y3 = z3 + vd;
            y0 = (y0 > 0.f) ? y0 : NEG_SLOPE * y0;
            y1 = (y1 > 0.f) ? y1 : NEG_SLOPE * y1;
            y2 = (y2 > 0.f) ? y2 : NEG_SLOPE * y2;
            y3 = (y3 > 0.f) ? y3 : NEG_SLOPE * y3;
            const float w0 = v0 ? __expf(y0) : 0.f;
            const float w1 = v1 ? __expf(y1) : 0.f;
            const float w2 = v2 ? __expf(y2) : 0.f;
            const float w3 = v3 ? __expf(y3) : 0.f;

            den += (w0 + w1) + (w2 + w3);
            a0 = fmaf(w0, bf2f((ushortT)(p0 & 0xFFFF)), a0);
            a1 = fmaf(w0, bf2f((ushortT)(p0 >> 16)), a1);
            a0 = fmaf(w1, bf2f((ushortT)(p1 & 0xFFFF)), a0);
            a1 = fmaf(w1, bf2f((ushortT)(p1 >> 16)), a1);
            a0 = fmaf(w2, bf2f((ushortT)(p2 & 0xFFFF)), a0);
            a1 = fmaf(w2, bf2f((ushortT)(p2 >> 16)), a1);
            a0 = fmaf(w3, bf2f((ushortT)(p3 & 0xFFFF)), a0);
            a1 = fmaf(w3, bf2f((ushortT)(p3 >> 16)), a1);
        }

        // reduce across the 4 edge-groups (xor 16 flips g bit0, xor 32 bit1)
        den += __shfl_xor(den, 16, 64); den += __shfl_xor(den, 32, 64);
        a0  += __shfl_xor(a0, 16, 64);  a0  += __shfl_xor(a0, 32, 64);
        a1  += __shfl_xor(a1, 16, 64);  a1  += __shfl_xor(a1, 32, 64);

        const float sc = 0.25f / (den + 1e-12f);
        if (l < 16) {
            const unsigned int pk =
                (unsigned int)f2bf(a0 * sc) | ((unsigned int)f2bf(a1 * sc) << 16);
            *reinterpret_cast<unsigned int*>(&tp[2 * q]) = pk;
        }
    }
}

// ---------------------------------------------------------------------------
// Combine: out[n][d] = sum_h tmp[h][n][d]  (1/4 already folded in).
// ---------------------------------------------------------------------------
__global__ void __launch_bounds__(256) k_comb(
    const ushortT* __restrict__ tmp, float* __restrict__ out, int N)
{
    const int idx = blockIdx.x * 256 + threadIdx.x;   // over N*8 (4 dims each)
    if (idx >= N * 8) return;
    const int n = idx >> 3, dg = idx & 7;

    float4 o = make_float4(0.f, 0.f, 0.f, 0.f);
#pragma unroll
    for (int h = 0; h < HEADS; ++h) {
        const ushort4 u = *reinterpret_cast<const ushort4*>(
            &tmp[((size_t)h * N + n) * 32 + dg * 4]);
        o.x += bf2f(u.x); o.y += bf2f(u.y); o.z += bf2f(u.z); o.w += bf2f(u.w);
    }
    *reinterpret_cast<float4*>(&out[(size_t)n * 32 + dg * 4]) = o;
}

extern "C" void kernel_launch(void* const* d_in, const int* in_sizes, int n_in,
                              void* d_out, int out_size, void* d_ws, size_t ws_size,
                              hipStream_t stream)
{
    const float* x      = (const float*)d_in[0];
    const int*   eidx   = (const int*)d_in[1];
    const float* W      = (const float*)d_in[2];
    const float* a_src  = (const float*)d_in[3];
    const float* a_dst  = (const float*)d_in[4];
    float* out = (float*)d_out;

    const int N = in_sizes[0] / IN_DIM;
    const int E = in_sizes[1] / 2;
    const int* src = eidx;       // edge_index[0, :]
    const int* dst = eidx + E;   // edge_index[1, :]

    const int nbins = (N + BIN_NODES - 1) >> BIN_SHIFT;   // 1563 for N=50000

    // workspace: h_pl 12.8MB | tmp 12.8MB | s_srcH .8MB | s_dstH .8MB |
    //            Wt_g 32KB | bin_buf 6.4MB | bin_cursor 6.3KB  -> ~33.7MB
    char* wsp = (char*)d_ws;
    ushortT* h_pl   = (ushortT*)wsp;  wsp += (size_t)N * HD * sizeof(ushortT);
    ushortT* tmp    = (ushortT*)wsp;  wsp += (size_t)HEADS * N * ODIM * sizeof(ushortT);
    float* s_srcH   = (float*)wsp;    wsp += (size_t)HEADS * N * sizeof(float);
    float* s_dstH   = (float*)wsp;    wsp += (size_t)HEADS * N * sizeof(float);
    ushortT* Wt_g   = (ushortT*)wsp;  wsp += (size_t)128 * 128 * sizeof(ushortT);
    int* bin_buf    = (int*)wsp;      wsp += (size_t)nbins * BINCAP * sizeof(int);
    int* bin_cursor = (int*)wsp;      wsp += (size_t)nbins * sizeof(int);

    hipMemsetAsync(bin_cursor, 0, (size_t)nbins * sizeof(int), stream);

    // 0) one-time W convert+transpose to bf16
    k_wconv<<<64, 256, 0, stream>>>(W, Wt_g);

    // 1) h = x@W via bf16 MFMA -> head planes
    k_gemm_mfma<<<(N + GM - 1) / GM, 256, 0, stream>>>(x, Wt_g, h_pl, N);

    // 1b) per-node attention scalars
    k_s<<<(N + 3) / 4, 256, 0, stream>>>(h_pl, a_src, a_dst, s_srcH, s_dstH, N);

    // 2) bin edges by dst/32
    {
        const int epb = 256 * KE;
        k_bin<<<(E + epb - 1) / epb, 256, 0, stream>>>(src, dst, bin_cursor,
                                                       bin_buf, E, nbins);
    }
    // 3) head-split pull (head = slow dim -> per-XCD L2 residency)
    {
        dim3 grid(nbins, HEADS);
        k_pull_h<<<grid, 256, 0, stream>>>(bin_buf, bin_cursor, h_pl,
                                           s_srcH, s_dstH, tmp, N);
    }
    // 4) combine heads
    k_comb<<<(N * 8 + 255) / 256, 256, 0, stream>>>(tmp, out, N);
}

// Round 9
// 104.826 us; speedup vs baseline: 1.0766x; 1.0766x over previous
//
#include <hip/hip_runtime.h>
#include <hip/hip_bf16.h>

#define IN_DIM 128
#define HEADS 4
#define ODIM 32
#define HD (HEADS * ODIM) // 128
#define NEG_SLOPE 0.2f

#define GM 64             // nodes per block in MFMA GEMM
#define LDK 136           // padded k-stride (bf16 elems)

#define BIN_SHIFT 5
#define BIN_NODES 32      // dst nodes per bin
#define BINCAP 1024       // max edges per bin (mean 512)
#define MAXBINS 2048      // LDS sizing in k_bin (nbins = 1563 for N=50000)
#define KE 16             // edges per thread in k_bin

typedef unsigned short ushortT;
typedef __attribute__((ext_vector_type(8))) short bf16x8;
typedef __attribute__((ext_vector_type(4))) float f32x4;

static __device__ __forceinline__ ushortT f2bf(float f) {
    __hip_bfloat16 b = __float2bfloat16(f); // RNE
    return *reinterpret_cast<ushortT*>(&b);
}
static __device__ __forceinline__ float bf2f(ushortT u) {
    unsigned int x = ((unsigned int)u) << 16;
    return __uint_as_float(x);
}
static __device__ __forceinline__ float hsel(float4 v, int head) {
    return (head == 0) ? v.x : (head == 1) ? v.y : (head == 2) ? v.z : v.w;
}

// ---------------------------------------------------------------------------
// One-time W convert+transpose: Wt_g[c][k] = bf16(W[k][c]). 16384 elems.
// ---------------------------------------------------------------------------
__global__ void __launch_bounds__(256) k_wconv(
    const float* __restrict__ W, ushortT* __restrict__ Wt_g)
{
    const int idx = blockIdx.x * 256 + threadIdx.x;  // 0..16383
    const int c = idx >> 7, k = idx & 127;
    Wt_g[c * 128 + k] = f2bf(W[k * HD + c]);
}

// ---------------------------------------------------------------------------
// Kernel 1: h = x @ W via bf16 MFMA (16x16x32), fp32 accumulate, bf16 out
// interleaved [N][128]. W staged as pure vector copy of pre-transposed bf16.
// ---------------------------------------------------------------------------
__global__ void __launch_bounds__(256) k_gemm_mfma(
    const float* __restrict__ x, const ushortT* __restrict__ Wt_g,
    ushortT* __restrict__ h_bf, int N)
{
    __shared__ ushortT Xs[GM * LDK];
    __shared__ ushortT Wt[128 * LDK];

    const int t  = threadIdx.x;
    const int n0 = blockIdx.x * GM;

    {   // stage Wt: vector copy
#pragma unroll
        for (int it = 0; it < 8; ++it) {
            const int o = it * 2048 + t * 8;      // linear ushort offset
            *reinterpret_cast<uint4*>(&Wt[(o >> 7) * LDK + (o & 127)]) =
                *reinterpret_cast<const uint4*>(&Wt_g[o]);
        }
    }
    {   // stage x as bf16: Xs[r][k]
        const int r  = t >> 2;          // 0..63
        const int k0 = (t & 3) * 32;
        const int ng = n0 + r;
        if (ng < N) {
#pragma unroll
            for (int kk = 0; kk < 32; kk += 4) {
                float4 v = *reinterpret_cast<const float4*>(
                    &x[(size_t)ng * IN_DIM + k0 + kk]);
                ushort4 u;
                u.x = f2bf(v.x); u.y = f2bf(v.y); u.z = f2bf(v.z); u.w = f2bf(v.w);
                *reinterpret_cast<ushort4*>(&Xs[r * LDK + k0 + kk]) = u;
            }
        } else {
#pragma unroll
            for (int kk = 0; kk < 32; kk += 4)
                *reinterpret_cast<ushort4*>(&Xs[r * LDK + k0 + kk]) =
                    make_ushort4(0, 0, 0, 0);
        }
    }
    __syncthreads();

    const int w  = t >> 6;
    const int l  = t & 63;
    const int lr = l & 15;
    const int lk = (l >> 4) * 8;

    f32x4 acc[8];
#pragma unroll
    for (int i = 0; i < 8; ++i) acc[i] = (f32x4)(0.f);

#pragma unroll
    for (int kt = 0; kt < 4; ++kt) {
        const bf16x8 af = *reinterpret_cast<const bf16x8*>(
            &Xs[(w * 16 + lr) * LDK + kt * 32 + lk]);
#pragma unroll
        for (int ct = 0; ct < 8; ++ct) {
            const bf16x8 bfr = *reinterpret_cast<const bf16x8*>(
                &Wt[(ct * 16 + lr) * LDK + kt * 32 + lk]);
            acc[ct] = __builtin_amdgcn_mfma_f32_16x16x32_bf16(af, bfr, acc[ct],
                                                              0, 0, 0);
        }
    }

    // C layout (m89): col = l&15, row = (l>>4)*4 + j
    const int rbase = w * 16 + (l >> 4) * 4;
#pragma unroll
    for (int ct = 0; ct < 8; ++ct) {
#pragma unroll
        for (int j = 0; j < 4; ++j) {
            const int ng = n0 + rbase + j;
            if (ng < N)
                h_bf[(size_t)ng * HD + ct * 16 + lr] = f2bf(acc[ct][j]);
        }
    }
}

// ---------------------------------------------------------------------------
// Kernel 1b: per-node attention scalars. One wave per node: lane l holds
// dims 2l,2l+1; 16-lane-group reduce per head (a_* flat [H*D]=[128]).
// ---------------------------------------------------------------------------
__global__ void __launch_bounds__(256) k_s(
    const ushortT* __restrict__ h_bf,
    const float* __restrict__ a_src, const float* __restrict__ a_dst,
    float* __restrict__ s_src, float* __restrict__ s_dst, int N)
{
    const int wid = (blockIdx.x * blockDim.x + threadIdx.x) >> 6;
    if (wid >= N) return;
    const int l = threadIdx.x & 63;

    const float as0 = a_src[2 * l], as1 = a_src[2 * l + 1];
    const float ad0 = a_dst[2 * l], ad1 = a_dst[2 * l + 1];

    const unsigned int pk = *reinterpret_cast<const unsigned int*>(
        &h_bf[(size_t)wid * HD + 2 * l]);
    const float f0 = bf2f((ushortT)(pk & 0xFFFF));
    const float f1 = bf2f((ushortT)(pk >> 16));

    float ps = f0 * as0 + f1 * as1;
    float pd = f0 * ad0 + f1 * ad1;
#pragma unroll
    for (int o = 1; o <= 8; o <<= 1) {
        ps += __shfl_xor(ps, o, 64);
        pd += __shfl_xor(pd, o, 64);
    }
    if ((l & 15) == 0) {
        s_src[wid * HEADS + (l >> 4)] = ps;
        s_dst[wid * HEADS + (l >> 4)] = pd;
    }
}

// ---------------------------------------------------------------------------
// Pass A: LDS-staged binning (proven, unchanged).
// ---------------------------------------------------------------------------
__global__ void __launch_bounds__(256) k_bin(
    const int* __restrict__ src, const int* __restrict__ dst,
    int* __restrict__ bin_cursor, int* __restrict__ bin_buf,
    int E, int nbins)
{
    __shared__ int lcnt[MAXBINS];
    __shared__ int lcur[MAXBINS];
    const int t = threadIdx.x;
    for (int i = t; i < nbins; i += 256) lcnt[i] = 0;
    __syncthreads();

    const int base_e = blockIdx.x * (256 * KE);
    int b_[KE]; int p_[KE];
#pragma unroll
    for (int k = 0; k < KE; ++k) {
        const int e = base_e + k * 256 + t;
        if (e < E) {
            const int d = dst[e];
            const int s = src[e];
            b_[k] = d >> BIN_SHIFT;
            p_[k] = ((d & (BIN_NODES - 1)) << 16) | s;
            atomicAdd(&lcnt[b_[k]], 1);
        } else {
            b_[k] = -1;
        }
    }
    __syncthreads();
    for (int i = t; i < nbins; i += 256) {
        const int c = lcnt[i];
        lcur[i] = (c > 0) ? atomicAdd(&bin_cursor[i], c) : 0;
    }
    __syncthreads();
#pragma unroll
    for (int k = 0; k < KE; ++k) {
        if (b_[k] >= 0) {
            const int pos = atomicAdd(&lcur[b_[k]], 1);
            if (pos < BINCAP) bin_buf[b_[k] * BINCAP + pos] = p_[k];
        }
    }
}

// ---------------------------------------------------------------------------
// Pass B fused with pull: one block (512 thr, 8 waves) per bin of 32 nodes.
// CSR built in LDS; each wave owns 4 nodes; per node two half-waves with
// 8-edge unroll -> 16 independent h-row + s_src gathers in flight per wave.
// ---------------------------------------------------------------------------
__global__ void __launch_bounds__(512) k_pull_binned(
    const int* __restrict__ bin_buf, const int* __restrict__ bin_cursor,
    const ushortT* __restrict__ h_bf,
    const float* __restrict__ s_src, const float* __restrict__ s_dst,
    float* __restrict__ out, int N)
{
    __shared__ ushortT csr[BINCAP];
    __shared__ int cnt_s[BIN_NODES], start_s[BIN_NODES], cur_s[BIN_NODES];

    const int b = blockIdx.x;
    const int t = threadIdx.x;
    const int node0 = b << BIN_SHIFT;

    int nedge = bin_cursor[b];
    nedge = (nedge < BINCAP) ? nedge : BINCAP;

    if (t < BIN_NODES) cnt_s[t] = 0;
    __syncthreads();

    for (int i = t; i < nedge; i += 512)
        atomicAdd(&cnt_s[bin_buf[b * BINCAP + i] >> 16], 1);
    __syncthreads();

    if (t < 32) {
        const int v = cnt_s[t];
        int inc = v;
#pragma unroll
        for (int o = 1; o < 32; o <<= 1) {
            const int x = __shfl_up(inc, o, 32);
            if (t >= o) inc += x;
        }
        start_s[t] = inc - v;
        cur_s[t]   = inc - v;
    }
    __syncthreads();

    for (int i = t; i < nedge; i += 512) {
        const int p = bin_buf[b * BINCAP + i];
        const int pos = atomicAdd(&cur_s[p >> 16], 1);
        csr[pos] = (ushortT)(p & 0xFFFF);
    }
    __syncthreads();

    const int wv   = t >> 6;       // wave 0..7
    const int l    = t & 63;
    const int half = l >> 5;
    const int l32  = l & 31;
    const int head = l32 >> 3;
    const int hoff = head * 8 + (l32 & 7);

    const ushort4* h4  = reinterpret_cast<const ushort4*>(h_bf);
    const float4*  ss4 = reinterpret_cast<const float4*>(s_src);

    for (int k = 0; k < 4; ++k) {
        const int nloc = wv * 4 + k;
        const int n = node0 + nloc;
        if (n >= N) break;

        const int st  = start_s[nloc];
        const int deg = cnt_s[nloc];
        const float4 vd4 = reinterpret_cast<const float4*>(s_dst)[n];
        const float vd = hsel(vd4, head);

        float den = 0.f;
        float a0 = 0.f, a1 = 0.f, a2 = 0.f, a3 = 0.f;

        const int count = (deg - half + 1) >> 1;   // edges for this half-wave
        for (int j = 0; j < count; j += 8) {
            int sidx[8]; bool val[8];
#pragma unroll
            for (int m = 0; m < 8; ++m) {
                val[m] = (j + m) < count;
                sidx[m] = csr[st + 2 * (val[m] ? (j + m) : j) + half];
            }

            // issue all 16 gathers up front (independent)
            float4 w_[8]; ushort4 q_[8];
#pragma unroll
            for (int m = 0; m < 8; ++m) {
                w_[m] = ss4[sidx[m]];
                q_[m] = h4[(size_t)sidx[m] * 32 + hoff];
            }

#pragma unroll
            for (int m = 0; m < 8; ++m) {
                float e = hsel(w_[m], head) + vd;
                e = (e > 0.f) ? e : NEG_SLOPE * e;
                const float xw = val[m] ? __expf(e) : 0.f;
                den += xw;
                a0 = fmaf(xw, bf2f(q_[m].x), a0);
                a1 = fmaf(xw, bf2f(q_[m].y), a1);
                a2 = fmaf(xw, bf2f(q_[m].z), a2);
                a3 = fmaf(xw, bf2f(q_[m].w), a3);
            }
        }

        // combine the two half-waves
        a0 += __shfl_xor(a0, 32, 64);
        a1 += __shfl_xor(a1, 32, 64);
        a2 += __shfl_xor(a2, 32, 64);
        a3 += __shfl_xor(a3, 32, 64);
        den += __shfl_xor(den, 32, 64);

        const float inv = 1.f / (den + 1e-12f);
        a0 *= inv; a1 *= inv; a2 *= inv; a3 *= inv;

        // head-mean across lanes (xor 8, 16 flips head bits)
        a0 += __shfl_xor(a0, 8, 64);  a0 += __shfl_xor(a0, 16, 64);
        a1 += __shfl_xor(a1, 8, 64);  a1 += __shfl_xor(a1, 16, 64);
        a2 += __shfl_xor(a2, 8, 64);  a2 += __shfl_xor(a2, 16, 64);
        a3 += __shfl_xor(a3, 8, 64);  a3 += __shfl_xor(a3, 16, 64);

        if (l < 8) {
            float4 o4 = make_float4(0.25f * a0, 0.25f * a1, 0.25f * a2, 0.25f * a3);
            *reinterpret_cast<float4*>(&out[(size_t)n * ODIM + l * 4]) = o4;
        }
    }
}

extern "C" void kernel_launch(void* const* d_in, const int* in_sizes, int n_in,
                              void* d_out, int out_size, void* d_ws, size_t ws_size,
                              hipStream_t stream)
{
    const float* x      = (const float*)d_in[0];
    const int*   eidx   = (const int*)d_in[1];
    const float* W      = (const float*)d_in[2];
    const float* a_src  = (const float*)d_in[3];
    const float* a_dst  = (const float*)d_in[4];
    float* out = (float*)d_out;

    const int N = in_sizes[0] / IN_DIM;
    const int E = in_sizes[1] / 2;
    const int* src = eidx;       // edge_index[0, :]
    const int* dst = eidx + E;   // edge_index[1, :]

    const int nbins = (N + BIN_NODES - 1) >> BIN_SHIFT;   // 1563 for N=50000

    // workspace: h_bf 12.8MB | s_src .8MB | s_dst .8MB | Wt_g 32KB |
    //            bin_buf 6.4MB | bin_cursor 6.3KB  -> ~21MB
    char* wsp = (char*)d_ws;
    ushortT* h_bf   = (ushortT*)wsp;  wsp += (size_t)N * HD * sizeof(ushortT);
    float* s_src    = (float*)wsp;    wsp += (size_t)N * HEADS * sizeof(float);
    float* s_dst    = (float*)wsp;    wsp += (size_t)N * HEADS * sizeof(float);
    ushortT* Wt_g   = (ushortT*)wsp;  wsp += (size_t)128 * 128 * sizeof(ushortT);
    int* bin_buf    = (int*)wsp;      wsp += (size_t)nbins * BINCAP * sizeof(int);
    int* bin_cursor = (int*)wsp;      wsp += (size_t)nbins * sizeof(int);

    hipMemsetAsync(bin_cursor, 0, (size_t)nbins * sizeof(int), stream);

    // 0) one-time W convert+transpose to bf16
    k_wconv<<<64, 256, 0, stream>>>(W, Wt_g);

    // 1) h = x@W via bf16 MFMA
    k_gemm_mfma<<<(N + GM - 1) / GM, 256, 0, stream>>>(x, Wt_g, h_bf, N);

    // 1b) per-node attention scalars
    k_s<<<(N + 3) / 4, 256, 0, stream>>>(h_bf, a_src, a_dst, s_src, s_dst, N);

    // 2) bin edges by dst/32
    {
        const int epb = 256 * KE;
        k_bin<<<(E + epb - 1) / epb, 256, 0, stream>>>(src, dst, bin_cursor,
                                                       bin_buf, E, nbins);
    }
    // 3) per-bin LDS CSR + pull (8 waves/block, 16 gathers in flight/wave)
    k_pull_binned<<<nbins, 512, 0, stream>>>(bin_buf, bin_cursor, h_bf,
                                             s_src, s_dst, out, N);
}

// Round 10
// 79.601 us; speedup vs baseline: 1.4178x; 1.3169x over previous
//
#include <hip/hip_runtime.h>
#include <hip/hip_bf16.h>

#define IN_DIM 128
#define HEADS 4
#define ODIM 32
#define HD (HEADS * ODIM) // 128
#define NEG_SLOPE 0.2f

#define GM 64             // nodes per block in MFMA GEMM
#define LDK 136           // padded k-stride (bf16 elems)

#define BIN_SHIFT 5
#define BIN_NODES 32      // dst nodes per bin
#define BINCAP 1024       // max edges per bin (mean 512)
#define MAXBINS 2048      // LDS sizing for bin branch (nbins = 1563)
#define KE 16             // edges per thread in bin branch

#define SMEM_BYTES 52224  // (GM+128)*LDK*2 = gemm branch need; >= bin's 16KB

typedef unsigned short ushortT;
typedef __attribute__((ext_vector_type(8))) short bf16x8;
typedef __attribute__((ext_vector_type(4))) float f32x4;

static __device__ __forceinline__ ushortT f2bf(float f) {
    __hip_bfloat16 b = __float2bfloat16(f); // RNE
    return *reinterpret_cast<ushortT*>(&b);
}
static __device__ __forceinline__ float bf2f(ushortT u) {
    unsigned int x = ((unsigned int)u) << 16;
    return __uint_as_float(x);
}
static __device__ __forceinline__ float hsel(float4 v, int head) {
    return (head == 0) ? v.x : (head == 1) ? v.y : (head == 2) ? v.z : v.w;
}

// ---------------------------------------------------------------------------
// One-time W convert+transpose (Wt_g[c][k] = bf16(W[k][c])) + zero bin_cursor.
// ---------------------------------------------------------------------------
__global__ void __launch_bounds__(256) k_wconv_zero(
    const float* __restrict__ W, ushortT* __restrict__ Wt_g,
    int* __restrict__ bin_cursor, int nbins)
{
    const int idx = blockIdx.x * 256 + threadIdx.x;  // 0..16383
    const int c = idx >> 7, k = idx & 127;
    Wt_g[c * 128 + k] = f2bf(W[k * HD + c]);
    if (idx < nbins) bin_cursor[idx] = 0;
}

// ---------------------------------------------------------------------------
// Mega kernel: blocks [0, nBinBlocks) run edge binning; the rest run the
// MFMA GEMM with fused s_src/s_dst epilogue. Branch is block-uniform.
// Shared memory overlaid (gemm: 52KB staging; bin: 16KB counters).
// ---------------------------------------------------------------------------
__global__ void __launch_bounds__(256) k_mega(
    const float* __restrict__ x, const ushortT* __restrict__ Wt_g,
    const float* __restrict__ a_src, const float* __restrict__ a_dst,
    const int* __restrict__ src, const int* __restrict__ dst,
    ushortT* __restrict__ h_bf, float* __restrict__ s_src, float* __restrict__ s_dst,
    int* __restrict__ bin_cursor, int* __restrict__ bin_buf,
    int N, int E, int nbins, int nBinBlocks)
{
    __shared__ __align__(16) char smem[SMEM_BYTES];
    const int t = threadIdx.x;

    if ((int)blockIdx.x < nBinBlocks) {
        // ---------------- bin branch ----------------
        int* lcnt = reinterpret_cast<int*>(smem);
        int* lcur = lcnt + MAXBINS;
        for (int i = t; i < nbins; i += 256) lcnt[i] = 0;
        __syncthreads();

        const int base_e = blockIdx.x * (256 * KE);
        int b_[KE]; int p_[KE];
#pragma unroll
        for (int k = 0; k < KE; ++k) {
            const int e = base_e + k * 256 + t;   // coalesced
            if (e < E) {
                const int d = dst[e];
                const int s = src[e];
                b_[k] = d >> BIN_SHIFT;
                p_[k] = ((d & (BIN_NODES - 1)) << 16) | s;
                atomicAdd(&lcnt[b_[k]], 1);
            } else {
                b_[k] = -1;
            }
        }
        __syncthreads();
        for (int i = t; i < nbins; i += 256) {
            const int c = lcnt[i];
            lcur[i] = (c > 0) ? atomicAdd(&bin_cursor[i], c) : 0;
        }
        __syncthreads();
#pragma unroll
        for (int k = 0; k < KE; ++k) {
            if (b_[k] >= 0) {
                const int pos = atomicAdd(&lcur[b_[k]], 1);
                if (pos < BINCAP) bin_buf[b_[k] * BINCAP + pos] = p_[k];
            }
        }
        return;
    }

    // ---------------- gemm branch ----------------
    ushortT* Xs = reinterpret_cast<ushortT*>(smem);
    ushortT* Wt = Xs + GM * LDK;

    const int n0 = ((int)blockIdx.x - nBinBlocks) * GM;

    {   // stage Wt: vector copy of pre-transposed bf16
#pragma unroll
        for (int it = 0; it < 8; ++it) {
            const int o = it * 2048 + t * 8;      // linear ushort offset
            *reinterpret_cast<uint4*>(&Wt[(o >> 7) * LDK + (o & 127)]) =
                *reinterpret_cast<const uint4*>(&Wt_g[o]);
        }
    }
    {   // stage x as bf16: Xs[r][k]
        const int r  = t >> 2;          // 0..63
        const int k0 = (t & 3) * 32;
        const int ng = n0 + r;
        if (ng < N) {
#pragma unroll
            for (int kk = 0; kk < 32; kk += 4) {
                float4 v = *reinterpret_cast<const float4*>(
                    &x[(size_t)ng * IN_DIM + k0 + kk]);
                ushort4 u;
                u.x = f2bf(v.x); u.y = f2bf(v.y); u.z = f2bf(v.z); u.w = f2bf(v.w);
                *reinterpret_cast<ushort4*>(&Xs[r * LDK + k0 + kk]) = u;
            }
        } else {
#pragma unroll
            for (int kk = 0; kk < 32; kk += 4)
                *reinterpret_cast<ushort4*>(&Xs[r * LDK + k0 + kk]) =
                    make_ushort4(0, 0, 0, 0);
        }
    }
    __syncthreads();

    const int w  = t >> 6;          // wave 0..3
    const int l  = t & 63;
    const int lr = l & 15;
    const int lk = (l >> 4) * 8;

    f32x4 acc[8];
#pragma unroll
    for (int i = 0; i < 8; ++i) acc[i] = (f32x4)(0.f);

#pragma unroll
    for (int kt = 0; kt < 4; ++kt) {
        const bf16x8 af = *reinterpret_cast<const bf16x8*>(
            &Xs[(w * 16 + lr) * LDK + kt * 32 + lk]);
#pragma unroll
        for (int ct = 0; ct < 8; ++ct) {
            const bf16x8 bfr = *reinterpret_cast<const bf16x8*>(
                &Wt[(ct * 16 + lr) * LDK + kt * 32 + lk]);
            acc[ct] = __builtin_amdgcn_mfma_f32_16x16x32_bf16(af, bfr, acc[ct],
                                                              0, 0, 0);
        }
    }

    // attention vectors for this lane's 8 columns (flat col = ct*16+lr)
    float aSv[8], aDv[8];
#pragma unroll
    for (int ct = 0; ct < 8; ++ct) {
        aSv[ct] = a_src[ct * 16 + lr];
        aDv[ct] = a_dst[ct * 16 + lr];
    }

    // C layout (m89): col = l&15, row = (l>>4)*4 + j
    const int rbase = w * 16 + (l >> 4) * 4;

#pragma unroll
    for (int j = 0; j < 4; ++j) {
        const int ng = n0 + rbase + j;

        // h_bf store (8 scalar bf16 stores per j)
        if (ng < N) {
#pragma unroll
            for (int ct = 0; ct < 8; ++ct)
                h_bf[(size_t)ng * HD + ct * 16 + lr] = f2bf(acc[ct][j]);
        }

        // fused s_src/s_dst: per-head dot across the 16 lr-lanes
        float ps[4] = {0.f, 0.f, 0.f, 0.f}, pd[4] = {0.f, 0.f, 0.f, 0.f};
#pragma unroll
        for (int ct = 0; ct < 8; ++ct) {
            ps[ct >> 1] = fmaf(acc[ct][j], aSv[ct], ps[ct >> 1]);
            pd[ct >> 1] = fmaf(acc[ct][j], aDv[ct], pd[ct >> 1]);
        }
#pragma unroll
        for (int o = 1; o <= 8; o <<= 1) {
#pragma unroll
            for (int hh = 0; hh < 4; ++hh) {
                ps[hh] += __shfl_xor(ps[hh], o, 64);
                pd[hh] += __shfl_xor(pd[hh], o, 64);
            }
        }
        if (lr == 0 && ng < N) {
            *reinterpret_cast<float4*>(&s_src[ng * 4]) =
                make_float4(ps[0], ps[1], ps[2], ps[3]);
            *reinterpret_cast<float4*>(&s_dst[ng * 4]) =
                make_float4(pd[0], pd[1], pd[2], pd[3]);
        }
    }
}

// ---------------------------------------------------------------------------
// Pull (r6-proven version, verbatim): one block (256 thr) per bin of 32
// nodes; LDS CSR; each wave 8 nodes; two half-waves with 4-edge unroll ->
// 8 independent gathers in flight per wave. No global atomics.
// ---------------------------------------------------------------------------
__global__ void __launch_bounds__(256) k_pull_binned(
    const int* __restrict__ bin_buf, const int* __restrict__ bin_cursor,
    const ushortT* __restrict__ h_bf,
    const float* __restrict__ s_src, const float* __restrict__ s_dst,
    float* __restrict__ out, int N)
{
    __shared__ ushortT csr[BINCAP];
    __shared__ int cnt_s[BIN_NODES], start_s[BIN_NODES], cur_s[BIN_NODES];

    const int b = blockIdx.x;
    const int t = threadIdx.x;
    const int node0 = b << BIN_SHIFT;

    int nedge = bin_cursor[b];
    nedge = (nedge < BINCAP) ? nedge : BINCAP;

    if (t < BIN_NODES) cnt_s[t] = 0;
    __syncthreads();

    for (int i = t; i < nedge; i += 256)
        atomicAdd(&cnt_s[bin_buf[b * BINCAP + i] >> 16], 1);
    __syncthreads();

    if (t < 32) {
        const int v = cnt_s[t];
        int inc = v;
#pragma unroll
        for (int o = 1; o < 32; o <<= 1) {
            const int x = __shfl_up(inc, o, 32);
            if (t >= o) inc += x;
        }
        start_s[t] = inc - v;
        cur_s[t]   = inc - v;
    }
    __syncthreads();

    for (int i = t; i < nedge; i += 256) {
        const int p = bin_buf[b * BINCAP + i];
        const int pos = atomicAdd(&cur_s[p >> 16], 1);
        csr[pos] = (ushortT)(p & 0xFFFF);
    }
    __syncthreads();

    const int wv   = t >> 6;
    const int l    = t & 63;
    const int half = l >> 5;
    const int l32  = l & 31;
    const int head = l32 >> 3;
    const int hoff = head * 8 + (l32 & 7);

    const ushort4* h4  = reinterpret_cast<const ushort4*>(h_bf);
    const float4*  ss4 = reinterpret_cast<const float4*>(s_src);

    for (int k = 0; k < 8; ++k) {
        const int nloc = wv * 8 + k;
        const int n = node0 + nloc;
        if (n >= N) break;

        const int st  = start_s[nloc];
        const int deg = cnt_s[nloc];
        const float4 vd4 = reinterpret_cast<const float4*>(s_dst)[n];
        const float vd = hsel(vd4, head);

        float den = 0.f;
        float a0 = 0.f, a1 = 0.f, a2 = 0.f, a3 = 0.f;

        const int count = (deg - half + 1) >> 1;
        for (int j = 0; j < count; j += 4) {
            const int i0 = st + 2 * j + half;
            const bool v1 = (j + 1) < count;
            const bool v2 = (j + 2) < count;
            const bool v3 = (j + 3) < count;
            const int s0 = csr[i0];
            const int s1 = v1 ? csr[i0 + 2] : s0;
            const int s2 = v2 ? csr[i0 + 4] : s0;
            const int s3 = v3 ? csr[i0 + 6] : s0;

            const float4 w0 = ss4[s0];
            const float4 w1 = ss4[s1];
            const float4 w2 = ss4[s2];
            const float4 w3 = ss4[s3];
            const ushort4 q0 = h4[(size_t)s0 * 32 + hoff];
            const ushort4 q1 = h4[(size_t)s1 * 32 + hoff];
            const ushort4 q2 = h4[(size_t)s2 * 32 + hoff];
            const ushort4 q3 = h4[(size_t)s3 * 32 + hoff];

            float e0 = hsel(w0, head) + vd;
            float e1 = hsel(w1, head) + vd;
            float e2 = hsel(w2, head) + vd;
            float e3 = hsel(w3, head) + vd;
            e0 = (e0 > 0.f) ? e0 : NEG_SLOPE * e0;
            e1 = (e1 > 0.f) ? e1 : NEG_SLOPE * e1;
            e2 = (e2 > 0.f) ? e2 : NEG_SLOPE * e2;
            e3 = (e3 > 0.f) ? e3 : NEG_SLOPE * e3;
            const float x0 = __expf(e0);
            const float x1 = v1 ? __expf(e1) : 0.f;
            const float x2 = v2 ? __expf(e2) : 0.f;
            const float x3 = v3 ? __expf(e3) : 0.f;

            den += (x0 + x1) + (x2 + x3);
            a0 = fmaf(x0, bf2f(q0.x), a0); a1 = fmaf(x0, bf2f(q0.y), a1);
            a2 = fmaf(x0, bf2f(q0.z), a2); a3 = fmaf(x0, bf2f(q0.w), a3);
            a0 = fmaf(x1, bf2f(q1.x), a0); a1 = fmaf(x1, bf2f(q1.y), a1);
            a2 = fmaf(x1, bf2f(q1.z), a2); a3 = fmaf(x1, bf2f(q1.w), a3);
            a0 = fmaf(x2, bf2f(q2.x), a0); a1 = fmaf(x2, bf2f(q2.y), a1);
            a2 = fmaf(x2, bf2f(q2.z), a2); a3 = fmaf(x2, bf2f(q2.w), a3);
            a0 = fmaf(x3, bf2f(q3.x), a0); a1 = fmaf(x3, bf2f(q3.y), a1);
            a2 = fmaf(x3, bf2f(q3.z), a2); a3 = fmaf(x3, bf2f(q3.w), a3);
        }

        a0 += __shfl_xor(a0, 32, 64);
        a1 += __shfl_xor(a1, 32, 64);
        a2 += __shfl_xor(a2, 32, 64);
        a3 += __shfl_xor(a3, 32, 64);
        den += __shfl_xor(den, 32, 64);

        const float inv = 1.f / (den + 1e-12f);
        a0 *= inv; a1 *= inv; a2 *= inv; a3 *= inv;

        a0 += __shfl_xor(a0, 8, 64);  a0 += __shfl_xor(a0, 16, 64);
        a1 += __shfl_xor(a1, 8, 64);  a1 += __shfl_xor(a1, 16, 64);
        a2 += __shfl_xor(a2, 8, 64);  a2 += __shfl_xor(a2, 16, 64);
        a3 += __shfl_xor(a3, 8, 64);  a3 += __shfl_xor(a3, 16, 64);

        if (l < 8) {
            float4 o4 = make_float4(0.25f * a0, 0.25f * a1, 0.25f * a2, 0.25f * a3);
            *reinterpret_cast<float4*>(&out[(size_t)n * ODIM + l * 4]) = o4;
        }
    }
}

extern "C" void kernel_launch(void* const* d_in, const int* in_sizes, int n_in,
                              void* d_out, int out_size, void* d_ws, size_t ws_size,
                              hipStream_t stream)
{
    const float* x      = (const float*)d_in[0];
    const int*   eidx   = (const int*)d_in[1];
    const float* W      = (const float*)d_in[2];
    const float* a_src  = (const float*)d_in[3];
    const float* a_dst  = (const float*)d_in[4];
    float* out = (float*)d_out;

    const int N = in_sizes[0] / IN_DIM;
    const int E = in_sizes[1] / 2;
    const int* src = eidx;       // edge_index[0, :]
    const int* dst = eidx + E;   // edge_index[1, :]

    const int nbins = (N + BIN_NODES - 1) >> BIN_SHIFT;   // 1563 for N=50000

    // workspace: h_bf 12.8MB | s_src .8MB | s_dst .8MB | Wt_g 32KB |
    //            bin_buf 6.4MB | bin_cursor 6.3KB  -> ~21MB
    char* wsp = (char*)d_ws;
    ushortT* h_bf   = (ushortT*)wsp;  wsp += (size_t)N * HD * sizeof(ushortT);
    float* s_src    = (float*)wsp;    wsp += (size_t)N * HEADS * sizeof(float);
    float* s_dst    = (float*)wsp;    wsp += (size_t)N * HEADS * sizeof(float);
    ushortT* Wt_g   = (ushortT*)wsp;  wsp += (size_t)128 * 128 * sizeof(ushortT);
    int* bin_buf    = (int*)wsp;      wsp += (size_t)nbins * BINCAP * sizeof(int);
    int* bin_cursor = (int*)wsp;      wsp += (size_t)nbins * sizeof(int);

    // 0) W convert/transpose + zero bin cursors (one dispatch)
    k_wconv_zero<<<64, 256, 0, stream>>>(W, Wt_g, bin_cursor, nbins);

    // 1) mega: binning blocks first (start early), then GEMM blocks
    {
        const int epb = 256 * KE;
        const int nBinBlocks  = (E + epb - 1) / epb;        // 196
        const int nGemmBlocks = (N + GM - 1) / GM;          // 782
        k_mega<<<nBinBlocks + nGemmBlocks, 256, 0, stream>>>(
            x, Wt_g, a_src, a_dst, src, dst,
            h_bf, s_src, s_dst, bin_cursor, bin_buf,
            N, E, nbins, nBinBlocks);
    }

    // 2) per-bin LDS CSR + pull
    k_pull_binned<<<nbins, 256, 0, stream>>>(bin_buf, bin_cursor, h_bf,
                                             s_src, s_dst, out, N);
}

// Round 11
// 73.998 us; speedup vs baseline: 1.5251x; 1.0757x over previous
//
#include <hip/hip_runtime.h>
#include <hip/hip_bf16.h>

#define IN_DIM 128
#define HEADS 4
#define ODIM 32
#define HD (HEADS * ODIM) // 128
#define NEG_SLOPE 0.2f

#define GM 64             // nodes per block in MFMA GEMM
#define LDK 136           // padded k-stride (bf16 elems)
#define ACCW 132          // fp32 acc LDS row stride (16B-aligned, low conflict)

#define BIN_SHIFT 5
#define BIN_NODES 32      // dst nodes per bin
#define BINCAP 1024       // max edges per bin (mean 512)
#define MAXBINS 2048      // LDS sizing for bin branch (nbins = 1563)
#define KE 16             // edges per thread in bin branch

#define SMEM_BYTES 52224  // gemm staging need; >= bin 16KB and acc 33.8KB

typedef unsigned short ushortT;
typedef __attribute__((ext_vector_type(8))) short bf16x8;
typedef __attribute__((ext_vector_type(4))) float f32x4;

static __device__ __forceinline__ ushortT f2bf(float f) {
    __hip_bfloat16 b = __float2bfloat16(f); // RNE
    return *reinterpret_cast<ushortT*>(&b);
}
static __device__ __forceinline__ float hsel(float4 v, int head) {
    return (head == 0) ? v.x : (head == 1) ? v.y : (head == 2) ? v.z : v.w;
}
// signed-byte lane sh (0,8,16,24) of packed uint -> float
static __device__ __forceinline__ float i8f(unsigned int p, int sh) {
    return (float)((int)(p << (24 - sh)) >> 24);
}

// ---------------------------------------------------------------------------
// One-time W convert+transpose (Wt_g[c][k] = bf16(W[k][c])) + zero bin_cursor.
// ---------------------------------------------------------------------------
__global__ void __launch_bounds__(256) k_wconv_zero(
    const float* __restrict__ W, ushortT* __restrict__ Wt_g,
    int* __restrict__ bin_cursor, int nbins)
{
    const int idx = blockIdx.x * 256 + threadIdx.x;  // 0..16383
    const int c = idx >> 7, k = idx & 127;
    Wt_g[c * 128 + k] = f2bf(W[k * HD + c]);
    if (idx < nbins) bin_cursor[idx] = 0;
}

// ---------------------------------------------------------------------------
// Mega kernel: blocks [0, nBinBlocks) bin edges; the rest run the MFMA GEMM
// with fused epilogues: s_src/s_dst (fp32, shfl) and h -> int8 + per-row
// scale (via LDS transpose). Shared memory overlaid across branches.
// ---------------------------------------------------------------------------
__global__ void __launch_bounds__(256) k_mega(
    const float* __restrict__ x, const ushortT* __restrict__ Wt_g,
    const float* __restrict__ a_src, const float* __restrict__ a_dst,
    const int* __restrict__ src, const int* __restrict__ dst,
    unsigned char* __restrict__ h8, float* __restrict__ scales,
    float* __restrict__ s_src, float* __restrict__ s_dst,
    int* __restrict__ bin_cursor, int* __restrict__ bin_buf,
    int N, int E, int nbins, int nBinBlocks)
{
    __shared__ __align__(16) char smem[SMEM_BYTES];
    const int t = threadIdx.x;

    if ((int)blockIdx.x < nBinBlocks) {
        // ---------------- bin branch ----------------
        int* lcnt = reinterpret_cast<int*>(smem);
        int* lcur = lcnt + MAXBINS;
        for (int i = t; i < nbins; i += 256) lcnt[i] = 0;
        __syncthreads();

        const int base_e = blockIdx.x * (256 * KE);
        int b_[KE]; int p_[KE];
#pragma unroll
        for (int k = 0; k < KE; ++k) {
            const int e = base_e + k * 256 + t;   // coalesced
            if (e < E) {
                const int d = dst[e];
                const int s = src[e];
                b_[k] = d >> BIN_SHIFT;
                p_[k] = ((d & (BIN_NODES - 1)) << 16) | s;
                atomicAdd(&lcnt[b_[k]], 1);
            } else {
                b_[k] = -1;
            }
        }
        __syncthreads();
        for (int i = t; i < nbins; i += 256) {
            const int c = lcnt[i];
            lcur[i] = (c > 0) ? atomicAdd(&bin_cursor[i], c) : 0;
        }
        __syncthreads();
#pragma unroll
        for (int k = 0; k < KE; ++k) {
            if (b_[k] >= 0) {
                const int pos = atomicAdd(&lcur[b_[k]], 1);
                if (pos < BINCAP) bin_buf[b_[k] * BINCAP + pos] = p_[k];
            }
        }
        return;
    }

    // ---------------- gemm branch ----------------
    ushortT* Xs = reinterpret_cast<ushortT*>(smem);
    ushortT* Wt = Xs + GM * LDK;

    const int n0 = ((int)blockIdx.x - nBinBlocks) * GM;

    {   // stage Wt: vector copy of pre-transposed bf16
#pragma unroll
        for (int it = 0; it < 8; ++it) {
            const int o = it * 2048 + t * 8;      // linear ushort offset
            *reinterpret_cast<uint4*>(&Wt[(o >> 7) * LDK + (o & 127)]) =
                *reinterpret_cast<const uint4*>(&Wt_g[o]);
        }
    }
    {   // stage x as bf16: Xs[r][k]
        const int r  = t >> 2;          // 0..63
        const int k0 = (t & 3) * 32;
        const int ng = n0 + r;
        if (ng < N) {
#pragma unroll
            for (int kk = 0; kk < 32; kk += 4) {
                float4 v = *reinterpret_cast<const float4*>(
                    &x[(size_t)ng * IN_DIM + k0 + kk]);
                ushort4 u;
                u.x = f2bf(v.x); u.y = f2bf(v.y); u.z = f2bf(v.z); u.w = f2bf(v.w);
                *reinterpret_cast<ushort4*>(&Xs[r * LDK + k0 + kk]) = u;
            }
        } else {
#pragma unroll
            for (int kk = 0; kk < 32; kk += 4)
                *reinterpret_cast<ushort4*>(&Xs[r * LDK + k0 + kk]) =
                    make_ushort4(0, 0, 0, 0);
        }
    }
    __syncthreads();

    const int w  = t >> 6;          // wave 0..3
    const int l  = t & 63;
    const int lr = l & 15;
    const int lk = (l >> 4) * 8;

    f32x4 acc[8];
#pragma unroll
    for (int i = 0; i < 8; ++i) acc[i] = (f32x4)(0.f);

#pragma unroll
    for (int kt = 0; kt < 4; ++kt) {
        const bf16x8 af = *reinterpret_cast<const bf16x8*>(
            &Xs[(w * 16 + lr) * LDK + kt * 32 + lk]);
#pragma unroll
        for (int ct = 0; ct < 8; ++ct) {
            const bf16x8 bfr = *reinterpret_cast<const bf16x8*>(
                &Wt[(ct * 16 + lr) * LDK + kt * 32 + lk]);
            acc[ct] = __builtin_amdgcn_mfma_f32_16x16x32_bf16(af, bfr, acc[ct],
                                                              0, 0, 0);
        }
    }

    // ---- s_src/s_dst epilogue (fp32 acc + shfl; proven in r10) ----
    float aSv[8], aDv[8];
#pragma unroll
    for (int ct = 0; ct < 8; ++ct) {
        aSv[ct] = a_src[ct * 16 + lr];
        aDv[ct] = a_dst[ct * 16 + lr];
    }
    const int rbase = w * 16 + (l >> 4) * 4;

#pragma unroll
    for (int j = 0; j < 4; ++j) {
        const int ng = n0 + rbase + j;
        float ps[4] = {0.f, 0.f, 0.f, 0.f}, pd[4] = {0.f, 0.f, 0.f, 0.f};
#pragma unroll
        for (int ct = 0; ct < 8; ++ct) {
            ps[ct >> 1] = fmaf(acc[ct][j], aSv[ct], ps[ct >> 1]);
            pd[ct >> 1] = fmaf(acc[ct][j], aDv[ct], pd[ct >> 1]);
        }
#pragma unroll
        for (int o = 1; o <= 8; o <<= 1) {
#pragma unroll
            for (int hh = 0; hh < 4; ++hh) {
                ps[hh] += __shfl_xor(ps[hh], o, 64);
                pd[hh] += __shfl_xor(pd[hh], o, 64);
            }
        }
        if (lr == 0 && ng < N) {
            *reinterpret_cast<float4*>(&s_src[ng * 4]) =
                make_float4(ps[0], ps[1], ps[2], ps[3]);
            *reinterpret_cast<float4*>(&s_dst[ng * 4]) =
                make_float4(pd[0], pd[1], pd[2], pd[3]);
        }
    }

    // ---- int8 h epilogue: LDS transpose -> row max -> quantize ----
    __syncthreads();                 // all waves done reading Xs/Wt
    float* accb = reinterpret_cast<float*>(smem);   // [GM][ACCW] fp32

#pragma unroll
    for (int ct = 0; ct < 8; ++ct)
#pragma unroll
        for (int j = 0; j < 4; ++j)
            accb[(rbase + j) * ACCW + ct * 16 + lr] = acc[ct][j];
    __syncthreads();

    {
        const int row = t >> 2;          // 0..63
        const int c0  = (t & 3) * 32;
        const int ng  = n0 + row;

        float4 v[8];
        float m = 0.f;
#pragma unroll
        for (int i = 0; i < 8; ++i) {
            v[i] = *reinterpret_cast<const float4*>(&accb[row * ACCW + c0 + 4 * i]);
            m = fmaxf(m, fmaxf(fmaxf(fabsf(v[i].x), fabsf(v[i].y)),
                               fmaxf(fabsf(v[i].z), fabsf(v[i].w))));
        }
        m = fmaxf(m, __shfl_xor(m, 1, 64));
        m = fmaxf(m, __shfl_xor(m, 2, 64));    // row max over the quad

        const float inv = (m > 0.f) ? 127.f / m : 0.f;
        unsigned int p[8];
#pragma unroll
        for (int i = 0; i < 8; ++i) {
            const int q0 = __float2int_rn(v[i].x * inv);
            const int q1 = __float2int_rn(v[i].y * inv);
            const int q2 = __float2int_rn(v[i].z * inv);
            const int q3 = __float2int_rn(v[i].w * inv);
            p[i] = (q0 & 0xFF) | ((q1 & 0xFF) << 8) |
                   ((q2 & 0xFF) << 16) | ((q3 & 0xFF) << 24);
        }
        if (ng < N) {
            *reinterpret_cast<uint4*>(&h8[(size_t)ng * 128 + c0]) =
                make_uint4(p[0], p[1], p[2], p[3]);
            *reinterpret_cast<uint4*>(&h8[(size_t)ng * 128 + c0 + 16]) =
                make_uint4(p[4], p[5], p[6], p[7]);
            if ((t & 3) == 0) scales[ng] = m * (1.f / 127.f);
        }
    }
}

// ---------------------------------------------------------------------------
// Pull: one block (256 thr) per bin of 32 nodes; LDS CSR; each wave 8 nodes;
// two half-waves with 4-edge unroll -> 8 independent row-gathers in flight.
// h is int8 (128 B/row, 2 lines/edge) + per-row scale folded into the weight.
// ---------------------------------------------------------------------------
__global__ void __launch_bounds__(256) k_pull_binned(
    const int* __restrict__ bin_buf, const int* __restrict__ bin_cursor,
    const unsigned char* __restrict__ h8, const float* __restrict__ scales,
    const float* __restrict__ s_src, const float* __restrict__ s_dst,
    float* __restrict__ out, int N)
{
    __shared__ ushortT csr[BINCAP];
    __shared__ int cnt_s[BIN_NODES], start_s[BIN_NODES], cur_s[BIN_NODES];

    const int b = blockIdx.x;
    const int t = threadIdx.x;
    const int node0 = b << BIN_SHIFT;

    int nedge = bin_cursor[b];
    nedge = (nedge < BINCAP) ? nedge : BINCAP;

    if (t < BIN_NODES) cnt_s[t] = 0;
    __syncthreads();

    for (int i = t; i < nedge; i += 256)
        atomicAdd(&cnt_s[bin_buf[b * BINCAP + i] >> 16], 1);
    __syncthreads();

    if (t < 32) {
        const int v = cnt_s[t];
        int inc = v;
#pragma unroll
        for (int o = 1; o < 32; o <<= 1) {
            const int x = __shfl_up(inc, o, 32);
            if (t >= o) inc += x;
        }
        start_s[t] = inc - v;
        cur_s[t]   = inc - v;
    }
    __syncthreads();

    for (int i = t; i < nedge; i += 256) {
        const int p = bin_buf[b * BINCAP + i];
        const int pos = atomicAdd(&cur_s[p >> 16], 1);
        csr[pos] = (ushortT)(p & 0xFFFF);
    }
    __syncthreads();

    const int wv   = t >> 6;
    const int l    = t & 63;
    const int half = l >> 5;
    const int l32  = l & 31;
    const int head = l32 >> 3;
    const int hoff = head * 8 + (l32 & 7);   // uint index within 32-uint row

    const unsigned int* hu = reinterpret_cast<const unsigned int*>(h8);
    const float4* ss4 = reinterpret_cast<const float4*>(s_src);

    for (int k = 0; k < 8; ++k) {
        const int nloc = wv * 8 + k;
        const int n = node0 + nloc;
        if (n >= N) break;

        const int st  = start_s[nloc];
        const int deg = cnt_s[nloc];
        const float4 vd4 = reinterpret_cast<const float4*>(s_dst)[n];
        const float vd = hsel(vd4, head);

        float den = 0.f;
        float a0 = 0.f, a1 = 0.f, a2 = 0.f, a3 = 0.f;

        const int count = (deg - half + 1) >> 1;
        for (int j = 0; j < count; j += 4) {
            const int i0 = st + 2 * j + half;
            const bool v1 = (j + 1) < count;
            const bool v2 = (j + 2) < count;
            const bool v3 = (j + 3) < count;
            const int s0 = csr[i0];
            const int s1 = v1 ? csr[i0 + 2] : s0;
            const int s2 = v2 ? csr[i0 + 4] : s0;
            const int s3 = v3 ? csr[i0 + 6] : s0;

            // issue all independent loads up front
            const float4 w0 = ss4[s0];
            const float4 w1 = ss4[s1];
            const float4 w2 = ss4[s2];
            const float4 w3 = ss4[s3];
            const float sc0 = scales[s0];
            const float sc1 = scales[s1];
            const float sc2 = scales[s2];
            const float sc3 = scales[s3];
            const unsigned int q0 = hu[(size_t)s0 * 32 + hoff];
            const unsigned int q1 = hu[(size_t)s1 * 32 + hoff];
            const unsigned int q2 = hu[(size_t)s2 * 32 + hoff];
            const unsigned int q3 = hu[(size_t)s3 * 32 + hoff];

            float e0 = hsel(w0, head) + vd;
            float e1 = hsel(w1, head) + vd;
            float e2 = hsel(w2, head) + vd;
            float e3 = hsel(w3, head) + vd;
            e0 = (e0 > 0.f) ? e0 : NEG_SLOPE * e0;
            e1 = (e1 > 0.f) ? e1 : NEG_SLOPE * e1;
            e2 = (e2 > 0.f) ? e2 : NEG_SLOPE * e2;
            e3 = (e3 > 0.f) ? e3 : NEG_SLOPE * e3;
            const float x0 = __expf(e0);
            const float x1 = v1 ? __expf(e1) : 0.f;
            const float x2 = v2 ? __expf(e2) : 0.f;
            const float x3 = v3 ? __expf(e3) : 0.f;

            den += (x0 + x1) + (x2 + x3);
            const float ws0 = x0 * sc0;
            const float ws1 = x1 * sc1;
            const float ws2 = x2 * sc2;
            const float ws3 = x3 * sc3;

            a0 = fmaf(ws0, i8f(q0, 0), a0);  a1 = fmaf(ws0, i8f(q0, 8), a1);
            a2 = fmaf(ws0, i8f(q0, 16), a2); a3 = fmaf(ws0, i8f(q0, 24), a3);
            a0 = fmaf(ws1, i8f(q1, 0), a0);  a1 = fmaf(ws1, i8f(q1, 8), a1);
            a2 = fmaf(ws1, i8f(q1, 16), a2); a3 = fmaf(ws1, i8f(q1, 24), a3);
            a0 = fmaf(ws2, i8f(q2, 0), a0);  a1 = fmaf(ws2, i8f(q2, 8), a1);
            a2 = fmaf(ws2, i8f(q2, 16), a2); a3 = fmaf(ws2, i8f(q2, 24), a3);
            a0 = fmaf(ws3, i8f(q3, 0), a0);  a1 = fmaf(ws3, i8f(q3, 8), a1);
            a2 = fmaf(ws3, i8f(q3, 16), a2); a3 = fmaf(ws3, i8f(q3, 24), a3);
        }

        // combine the two half-waves
        a0 += __shfl_xor(a0, 32, 64);
        a1 += __shfl_xor(a1, 32, 64);
        a2 += __shfl_xor(a2, 32, 64);
        a3 += __shfl_xor(a3, 32, 64);
        den += __shfl_xor(den, 32, 64);

        const float inv = 1.f / (den + 1e-12f);
        a0 *= inv; a1 *= inv; a2 *= inv; a3 *= inv;

        // head-mean across lanes (xor 8, 16 flips head bits)
        a0 += __shfl_xor(a0, 8, 64);  a0 += __shfl_xor(a0, 16, 64);
        a1 += __shfl_xor(a1, 8, 64);  a1 += __shfl_xor(a1, 16, 64);
        a2 += __shfl_xor(a2, 8, 64);  a2 += __shfl_xor(a2, 16, 64);
        a3 += __shfl_xor(a3, 8, 64);  a3 += __shfl_xor(a3, 16, 64);

        if (l < 8) {
            float4 o4 = make_float4(0.25f * a0, 0.25f * a1, 0.25f * a2, 0.25f * a3);
            *reinterpret_cast<float4*>(&out[(size_t)n * ODIM + l * 4]) = o4;
        }
    }
}

extern "C" void kernel_launch(void* const* d_in, const int* in_sizes, int n_in,
                              void* d_out, int out_size, void* d_ws, size_t ws_size,
                              hipStream_t stream)
{
    const float* x      = (const float*)d_in[0];
    const int*   eidx   = (const int*)d_in[1];
    const float* W      = (const float*)d_in[2];
    const float* a_src  = (const float*)d_in[3];
    const float* a_dst  = (const float*)d_in[4];
    float* out = (float*)d_out;

    const int N = in_sizes[0] / IN_DIM;
    const int E = in_sizes[1] / 2;
    const int* src = eidx;       // edge_index[0, :]
    const int* dst = eidx + E;   // edge_index[1, :]

    const int nbins = (N + BIN_NODES - 1) >> BIN_SHIFT;   // 1563 for N=50000

    // workspace: h8 6.4MB | scales .2MB | s_src .8MB | s_dst .8MB |
    //            Wt_g 32KB | bin_buf 6.4MB | bin_cursor 6.3KB  -> ~14.7MB
    char* wsp = (char*)d_ws;
    unsigned char* h8 = (unsigned char*)wsp; wsp += (size_t)N * 128;
    float* scales   = (float*)wsp;    wsp += (size_t)N * sizeof(float);
    float* s_src    = (float*)wsp;    wsp += (size_t)N * HEADS * sizeof(float);
    float* s_dst    = (float*)wsp;    wsp += (size_t)N * HEADS * sizeof(float);
    ushortT* Wt_g   = (ushortT*)wsp;  wsp += (size_t)128 * 128 * sizeof(ushortT);
    int* bin_buf    = (int*)wsp;      wsp += (size_t)nbins * BINCAP * sizeof(int);
    int* bin_cursor = (int*)wsp;      wsp += (size_t)nbins * sizeof(int);

    // 0) W convert/transpose + zero bin cursors
    k_wconv_zero<<<64, 256, 0, stream>>>(W, Wt_g, bin_cursor, nbins);

    // 1) mega: binning blocks first, then GEMM blocks
    {
        const int epb = 256 * KE;
        const int nBinBlocks  = (E + epb - 1) / epb;        // 196
        const int nGemmBlocks = (N + GM - 1) / GM;          // 782
        k_mega<<<nBinBlocks + nGemmBlocks, 256, 0, stream>>>(
            x, Wt_g, a_src, a_dst, src, dst,
            h8, scales, s_src, s_dst, bin_cursor, bin_buf,
            N, E, nbins, nBinBlocks);
    }

    // 2) per-bin LDS CSR + pull (int8 h)
    k_pull_binned<<<nbins, 256, 0, stream>>>(bin_buf, bin_cursor, h8, scales,
                                             s_src, s_dst, out, N);
}